// Round 1
// baseline (2590.742 us; speedup 1.0000x reference)
//
#include <hip/hip_runtime.h>
#include <math.h>

#define LYRS 6
#define BATCH 16
#define DIM 1024
#define NH 16
#define HDIM 64
#define FFNDIM 4096
#define VOCAB 32000
#define NCACHE 512
#define SRCLEN 512
#define SCALE 0.125f
#define EMB_SCALE 32.0f

__device__ __forceinline__ float wave_reduce_sum(float v){
#pragma unroll
  for (int off = 32; off; off >>= 1) v += __shfl_xor(v, off, 64);
  return v;
}
__device__ __forceinline__ float wave_reduce_max(float v){
#pragma unroll
  for (int off = 32; off; off >>= 1) v = fmaxf(v, __shfl_xor(v, off, 64));
  return v;
}

// h[b][d] = decoder_embed[b][d]*sqrt(D) + pe[cache_len][d]
__global__ __launch_bounds__(256) void k_embed(const float* __restrict__ de,
                                               const float* __restrict__ pe,
                                               const int* __restrict__ cl,
                                               float* __restrict__ h){
  int b = blockIdx.x, t = threadIdx.x;
  int c = cl[0];
  const float4* d4 = (const float4*)(de + (size_t)b * DIM);
  const float4* p4 = (const float4*)(pe + (size_t)c * DIM);
  float4* h4 = (float4*)(h + (size_t)b * DIM);
  float4 a = d4[t], p = p4[t];
  float4 o;
  o.x = a.x * EMB_SCALE + p.x; o.y = a.y * EMB_SCALE + p.y;
  o.z = a.z * EMB_SCALE + p.z; o.w = a.w * EMB_SCALE + p.w;
  h4[t] = o;
}

// encT[b][c][j] = enc[b][j][c]  (one-time, 64x64 tiles via LDS)
__global__ __launch_bounds__(256) void k_transpose(const float* __restrict__ enc,
                                                   float* __restrict__ encT){
  __shared__ float tile[64][65];
  int c0 = blockIdx.x * 64, j0 = blockIdx.y * 64, b = blockIdx.z;
  int tx = threadIdx.x, ty = threadIdx.y;
  const float* src = enc + (size_t)b * SRCLEN * DIM;
  float* dst = encT + (size_t)b * DIM * SRCLEN;
#pragma unroll
  for (int r = ty; r < 64; r += 4)
    tile[r][tx] = src[(size_t)(j0 + r) * DIM + c0 + tx];
  __syncthreads();
#pragma unroll
  for (int r = ty; r < 64; r += 4)
    dst[(size_t)(c0 + r) * SRCLEN + j0 + tx] = tile[tx][r];
}

// Generic batched small-M GEMV: C[bb][m][n] = sum_k A[bb][m][k]*W[bb][n][k] (+bias)
// flags: 1 = SiLU epilogue, 2 = accumulate into C. out2: optional mirror write [16][1024].
__global__ __launch_bounds__(256) void k_gemv16(
    const float* __restrict__ A, int a_rs, int a_bs,
    const float* __restrict__ W, int w_rs, int w_bs,
    const float* __restrict__ bias, int bias_bs,
    float* __restrict__ C, int c_rs, int c_bs,
    float* __restrict__ out2,
    int N, int K, int flags){
  extern __shared__ float Al[];
  int bb = blockIdx.y;
  int tid = threadIdx.x;
  const float* Ab = A + (size_t)bb * a_bs;
  for (int m = 0; m < 16; ++m)
    for (int k = tid; k < K; k += 256)
      Al[m * K + k] = Ab[(size_t)m * a_rs + k];
  __syncthreads();
  int wave = tid >> 6, lane = tid & 63;
  for (int n = blockIdx.x * 4 + wave; n < N; n += gridDim.x * 4){
    const float* wr = W + (size_t)bb * w_bs + (size_t)n * w_rs;
    float acc[16];
#pragma unroll
    for (int m = 0; m < 16; ++m) acc[m] = 0.f;
    for (int k = lane; k < K; k += 64){
      float wv = wr[k];
#pragma unroll
      for (int m = 0; m < 16; ++m) acc[m] = fmaf(wv, Al[m * K + k], acc[m]);
    }
#pragma unroll
    for (int m = 0; m < 16; ++m){
#pragma unroll
      for (int off = 32; off; off >>= 1) acc[m] += __shfl_xor(acc[m], off, 64);
    }
    if (lane < 16){
      float r = acc[0];
#pragma unroll
      for (int m = 1; m < 16; ++m) r = (lane == m) ? acc[m] : r;
      if (bias) r += bias[(size_t)bb * bias_bs + n];
      size_t ci = (size_t)bb * c_bs + (size_t)lane * c_rs + n;
      if (flags & 2) r += C[ci];
      if (flags & 1) r = r / (1.f + expf(-r));
      C[ci] = r;
      if (out2) out2[lane * DIM + n] = r;
    }
  }
}

// Self-attention per (b,h): 513 keys (512 cached + 1 new). Mask bias is a
// constant shift -> softmax-invariant -> skipped.
__global__ __launch_bounds__(512) void k_self_attn(
    const float* __restrict__ q, const float* __restrict__ kn,
    const float* __restrict__ vn, const float* __restrict__ pk,
    const float* __restrict__ pv, float* __restrict__ out){
  __shared__ float sc[513];
  __shared__ float red1[8], red2[8];
  __shared__ float o8[8 * 64];
  int bh = blockIdx.x, b = bh >> 4, hh = bh & 15;
  int tid = threadIdx.x, wave = tid >> 6, lane = tid & 63;
  size_t base = (size_t)b * NCACHE * DIM + hh * HDIM;
  float qd = q[b * DIM + hh * HDIM + lane] * SCALE;
  for (int j = wave; j < 513; j += 8){
    float kd = (j < NCACHE) ? pk[base + (size_t)j * DIM + lane]
                            : kn[b * DIM + hh * HDIM + lane];
    float p = wave_reduce_sum(qd * kd);
    if (lane == 0) sc[j] = p;
  }
  __syncthreads();
  float lm = -1e30f;
  for (int j = tid; j < 513; j += 512) lm = fmaxf(lm, sc[j]);
  lm = wave_reduce_max(lm);
  if (lane == 0) red1[wave] = lm;
  __syncthreads();
  float bm = red1[0];
#pragma unroll
  for (int w = 1; w < 8; ++w) bm = fmaxf(bm, red1[w]);
  float ls = 0.f;
  for (int j = tid; j < 513; j += 512){
    float e = expf(sc[j] - bm);
    sc[j] = e;
    ls += e;
  }
  ls = wave_reduce_sum(ls);
  if (lane == 0) red2[wave] = ls;
  __syncthreads();   // also publishes sc[j]=e to all threads
  float tot = 0.f;
#pragma unroll
  for (int w = 0; w < 8; ++w) tot += red2[w];
  float inv = 1.f / tot;
  float acc = 0.f;
  for (int j = wave; j < 513; j += 8){
    float vd = (j < NCACHE) ? pv[base + (size_t)j * DIM + lane]
                            : vn[b * DIM + hh * HDIM + lane];
    acc += sc[j] * vd;
  }
  o8[wave * 64 + lane] = acc;
  __syncthreads();
  if (tid < 64){
    float s2 = 0.f;
#pragma unroll
    for (int w = 0; w < 8; ++w) s2 += o8[w * 64 + tid];
    out[b * DIM + hh * HDIM + tid] = s2 * inv;
  }
}

// out = LayerNorm(res + x) * w + b, one block per row of 1024
__global__ __launch_bounds__(256) void k_add_ln(
    const float* __restrict__ res, const float* __restrict__ x,
    const float* __restrict__ w, const float* __restrict__ bln,
    float* __restrict__ out){
  __shared__ float r1[4], r2[4];
  int b = blockIdx.x, tid = threadIdx.x, wave = tid >> 6, lane = tid & 63;
  const float4* R = (const float4*)(res + (size_t)b * DIM);
  const float4* X = (const float4*)(x + (size_t)b * DIM);
  float4 rv = R[tid], xv = X[tid];
  float v0 = rv.x + xv.x, v1 = rv.y + xv.y, v2 = rv.z + xv.z, v3 = rv.w + xv.w;
  float s = v0 + v1 + v2 + v3;
  float sq = v0 * v0 + v1 * v1 + v2 * v2 + v3 * v3;
  s = wave_reduce_sum(s); sq = wave_reduce_sum(sq);
  if (lane == 0){ r1[wave] = s; r2[wave] = sq; }
  __syncthreads();
  float ts = r1[0] + r1[1] + r1[2] + r1[3];
  float tq = r2[0] + r2[1] + r2[2] + r2[3];
  float mean = ts * (1.f / DIM);
  float var = tq * (1.f / DIM) - mean * mean;
  float rstd = rsqrtf(var + 1e-5f);
  const float4* W4 = (const float4*)w;
  const float4* B4 = (const float4*)bln;
  float4 wv = W4[tid], bv = B4[tid];
  float4 o;
  o.x = (v0 - mean) * rstd * wv.x + bv.x;
  o.y = (v1 - mean) * rstd * wv.y + bv.y;
  o.z = (v2 - mean) * rstd * wv.z + bv.z;
  o.w = (v3 - mean) * rstd * wv.w + bv.w;
  ((float4*)(out + (size_t)b * DIM))[tid] = o;
}

// g[b][h][c] = sum_d (q[b][h*64+d]*SCALE) * kw[h*64+d][c]  (cross-attn K folded into query)
__global__ __launch_bounds__(256) void k_gmat(const float* __restrict__ q,
                                              const float* __restrict__ kw,
                                              float* __restrict__ g){
  __shared__ float ql[16 * 64];
  int hh = blockIdx.y;
  int c = blockIdx.x * 256 + threadIdx.x;
  for (int i = threadIdx.x; i < 16 * 64; i += 256){
    int b = i >> 6, d = i & 63;
    ql[i] = q[b * DIM + hh * HDIM + d] * SCALE;
  }
  __syncthreads();
  float acc[16];
#pragma unroll
  for (int m = 0; m < 16; ++m) acc[m] = 0.f;
  for (int d = 0; d < 64; ++d){
    float wv = kw[(size_t)(hh * HDIM + d) * DIM + c];
#pragma unroll
    for (int b = 0; b < 16; ++b) acc[b] = fmaf(ql[b * 64 + d], wv, acc[b]);
  }
#pragma unroll
  for (int b = 0; b < 16; ++b) g[(size_t)(b * NH + hh) * DIM + c] = acc[b];
}

// In-place softmax over rows of 512 (one block per (b,h))
__global__ __launch_bounds__(512) void k_softmax512(float* __restrict__ s){
  __shared__ float red[8];
  float* row = s + (size_t)blockIdx.x * SRCLEN;
  int tid = threadIdx.x, wave = tid >> 6, lane = tid & 63;
  float v = row[tid];
  float m = wave_reduce_max(v);
  if (lane == 0) red[wave] = m;
  __syncthreads();
  float bm = red[0];
#pragma unroll
  for (int w = 1; w < 8; ++w) bm = fmaxf(bm, red[w]);
  float e = expf(v - bm);
  __syncthreads();
  float ls = wave_reduce_sum(e);
  if (lane == 0) red[wave] = ls;
  __syncthreads();
  float tot = 0.f;
#pragma unroll
  for (int w = 0; w < 8; ++w) tot += red[w];
  row[tid] = e / tot;
}

extern "C" void kernel_launch(void* const* d_in, const int* in_sizes, int n_in,
                              void* d_out, int out_size, void* d_ws, size_t ws_size,
                              hipStream_t stream){
  const float* de   = (const float*)d_in[0];
  const float* enc  = (const float*)d_in[1];
  const float* pk   = (const float*)d_in[2];
  const float* pv   = (const float*)d_in[3];
  const int*   cl   = (const int*)d_in[4];
  const float* pe   = (const float*)d_in[5];
  const float* saqw = (const float*)d_in[6];
  const float* sakw = (const float*)d_in[7];
  const float* savw = (const float*)d_in[8];
  const float* saow = (const float*)d_in[9];
  const float* caqw = (const float*)d_in[10];
  const float* cakw = (const float*)d_in[11];
  const float* cavw = (const float*)d_in[12];
  const float* caow = (const float*)d_in[13];
  const float* saqb = (const float*)d_in[14];
  const float* sakb = (const float*)d_in[15];
  const float* savb = (const float*)d_in[16];
  const float* saob = (const float*)d_in[17];
  const float* caqb = (const float*)d_in[18];
  const float* cakb = (const float*)d_in[19];
  const float* cavb = (const float*)d_in[20];
  const float* caob = (const float*)d_in[21];
  const float* fc1w = (const float*)d_in[22];
  const float* fc1b = (const float*)d_in[23];
  const float* fc2w = (const float*)d_in[24];
  const float* fc2b = (const float*)d_in[25];
  const float* ln1w = (const float*)d_in[26];
  const float* ln2w = (const float*)d_in[27];
  const float* ln3w = (const float*)d_in[28];
  const float* ln1b = (const float*)d_in[29];
  const float* ln2b = (const float*)d_in[30];
  const float* ln3b = (const float*)d_in[31];
  const float* lmw  = (const float*)d_in[32];
  float* out = (float*)d_out;
  float* ws  = (float*)d_ws;

  float* h    = ws;             // [16][1024]
  float* qb   = ws + 16384;     // [16][1024]
  float* knew = ws + 32768;     // [16][1024]
  float* vnew = ws + 49152;     // [16][1024]
  float* attn = ws + 65536;     // [16][1024]
  float* tmp  = ws + 81920;     // [16][4096]
  float* tmp2 = ws + 147456;    // [16][1024]
  float* g    = ws + 163840;    // [16][16][1024]
  float* s    = ws + 425984;    // [16][16][512]
  float* ctx  = ws + 557056;    // [16][16][1024]
  float* encT = ws + 819200;    // [16][1024][512]

  const size_t KLDS = (size_t)DIM * 16 * 4;     // 64 KB
  const size_t JLDS = (size_t)SRCLEN * 16 * 4;  // 32 KB

  k_transpose<<<dim3(16, 8, 16), dim3(64, 4), 0, stream>>>(enc, encT);
  k_embed<<<16, 256, 0, stream>>>(de, pe, cl, h);

  for (int i = 0; i < LYRS; ++i){
    size_t wo = (size_t)i * DIM * DIM;
    size_t bo = (size_t)i * DIM;
    // ---- self-attention ----
    k_gemv16<<<dim3(256, 1), 256, KLDS, stream>>>(h, DIM, 0, saqw + wo, DIM, 0,
        saqb + bo, 0, qb, DIM, 0, nullptr, DIM, DIM, 0);
    k_gemv16<<<dim3(256, 1), 256, KLDS, stream>>>(h, DIM, 0, sakw + wo, DIM, 0,
        sakb + bo, 0, knew, DIM, 0, out + 512000 + (size_t)i * 16384, DIM, DIM, 0);
    k_gemv16<<<dim3(256, 1), 256, KLDS, stream>>>(h, DIM, 0, savw + wo, DIM, 0,
        savb + bo, 0, vnew, DIM, 0, out + 610304 + (size_t)i * 16384, DIM, DIM, 0);
    k_self_attn<<<256, 512, 0, stream>>>(qb, knew, vnew,
        pk + (size_t)i * BATCH * NCACHE * DIM, pv + (size_t)i * BATCH * NCACHE * DIM, attn);
    k_gemv16<<<dim3(256, 1), 256, KLDS, stream>>>(attn, DIM, 0, saow + wo, DIM, 0,
        saob + bo, 0, tmp2, DIM, 0, nullptr, DIM, DIM, 0);
    k_add_ln<<<16, 256, 0, stream>>>(h, tmp2, ln1w + bo, ln1b + bo, h);
    // ---- cross-attention (K/V projections folded around the softmax) ----
    k_gemv16<<<dim3(256, 1), 256, KLDS, stream>>>(h, DIM, 0, caqw + wo, DIM, 0,
        caqb + bo, 0, qb, DIM, 0, nullptr, DIM, DIM, 0);
    k_gmat<<<dim3(4, 16), 256, 0, stream>>>(qb, cakw + wo, g);
    k_gemv16<<<dim3(32, 16), 256, KLDS, stream>>>(g, DIM, NH * DIM, enc, DIM,
        SRCLEN * DIM, nullptr, 0, s, SRCLEN, NH * SRCLEN, nullptr, SRCLEN, DIM, 0);
    k_softmax512<<<256, 512, 0, stream>>>(s);
    k_gemv16<<<dim3(64, 16), 256, JLDS, stream>>>(s, SRCLEN, NH * SRCLEN, encT,
        SRCLEN, DIM * SRCLEN, nullptr, 0, ctx, DIM, NH * DIM, nullptr, DIM, SRCLEN, 0);
    k_gemv16<<<dim3(16, 16), 256, KLDS, stream>>>(ctx, NH * DIM, DIM, cavw + wo,
        DIM, HDIM * DIM, cavb + bo, HDIM, attn, DIM, HDIM, nullptr, HDIM, DIM, 0);
    k_gemv16<<<dim3(256, 1), 256, KLDS, stream>>>(attn, DIM, 0, caow + wo, DIM, 0,
        caob + bo, 0, tmp2, DIM, 0, nullptr, DIM, DIM, 0);
    k_add_ln<<<16, 256, 0, stream>>>(h, tmp2, ln2w + bo, ln2b + bo, h);
    // ---- FFN ----
    k_gemv16<<<dim3(256, 1), 256, KLDS, stream>>>(h, DIM, 0,
        fc1w + (size_t)i * FFNDIM * DIM, DIM, 0, fc1b + (size_t)i * FFNDIM, 0,
        tmp, FFNDIM, 0, nullptr, FFNDIM, DIM, 1);
    for (int c4 = 0; c4 < 4; ++c4){
      k_gemv16<<<dim3(256, 1), 256, KLDS, stream>>>(tmp + c4 * DIM, FFNDIM, 0,
          fc2w + (size_t)i * DIM * FFNDIM + c4 * DIM, FFNDIM, 0,
          c4 == 0 ? fc2b + bo : nullptr, 0,
          tmp2, DIM, 0, nullptr, DIM, DIM, c4 == 0 ? 0 : 2);
    }
    k_add_ln<<<16, 256, 0, stream>>>(h, tmp2, ln3w + bo, ln3b + bo, h);
  }
  // ---- lm_head ----
  k_gemv16<<<dim3(512, 1), 256, KLDS, stream>>>(h, DIM, 0, lmw, DIM, 0,
      nullptr, 0, out, VOCAB, 0, nullptr, VOCAB, DIM, 0);
}

// Round 2
// 1857.210 us; speedup vs baseline: 1.3950x; 1.3950x over previous
//
#include <hip/hip_runtime.h>
#include <math.h>

#define LYRS 6
#define BATCH 16
#define DIM 1024
#define NH 16
#define HDIM 64
#define FFNDIM 4096
#define VOCAB 32000
#define NCACHE 512
#define SRCLEN 512
#define SCALE 0.125f
#define EMB_SCALE 32.0f

__device__ __forceinline__ float wave_reduce_sum(float v){
#pragma unroll
  for (int off = 32; off; off >>= 1) v += __shfl_xor(v, off, 64);
  return v;
}
__device__ __forceinline__ float wave_reduce_max(float v){
#pragma unroll
  for (int off = 32; off; off >>= 1) v = fmaxf(v, __shfl_xor(v, off, 64));
  return v;
}

// h[b][d] = decoder_embed[b][d]*sqrt(D) + pe[cache_len][d]
__global__ __launch_bounds__(256) void k_embed(const float* __restrict__ de,
                                               const float* __restrict__ pe,
                                               const int* __restrict__ cl,
                                               float* __restrict__ h){
  int b = blockIdx.x, t = threadIdx.x;
  int c = cl[0];
  const float4* d4 = (const float4*)(de + (size_t)b * DIM);
  const float4* p4 = (const float4*)(pe + (size_t)c * DIM);
  float4* h4 = (float4*)(h + (size_t)b * DIM);
  float4 a = d4[t], p = p4[t];
  float4 o;
  o.x = a.x * EMB_SCALE + p.x; o.y = a.y * EMB_SCALE + p.y;
  o.z = a.z * EMB_SCALE + p.z; o.w = a.w * EMB_SCALE + p.w;
  h4[t] = o;
}

// encT[b][c][j] = enc[b][j][c]
__global__ __launch_bounds__(256) void k_transpose(const float* __restrict__ enc,
                                                   float* __restrict__ encT){
  __shared__ float tile[64][65];
  int c0 = blockIdx.x * 64, j0 = blockIdx.y * 64, b = blockIdx.z;
  int tx = threadIdx.x, ty = threadIdx.y;
  const float* src = enc + (size_t)b * SRCLEN * DIM;
  float* dst = encT + (size_t)b * DIM * SRCLEN;
#pragma unroll
  for (int r = ty; r < 64; r += 4)
    tile[r][tx] = src[(size_t)(j0 + r) * DIM + c0 + tx];
  __syncthreads();
#pragma unroll
  for (int r = ty; r < 64; r += 4)
    dst[(size_t)(c0 + r) * SRCLEN + j0 + tx] = tile[tx][r];
}

// ---------------------------------------------------------------------------
// Thread-owns-n GEMM: C[bb][m][n] = sum_k A[bb][m][k] * W[bb][n][k] (+bias)
// grid: (N/64, BB, KS). 4 waves split the block's k-range 4 ways.
// lane l owns column n = blockIdx.x*64 + l; 16 accumulators over m.
// A staged per-wave in LDS k-major -> per k: 4 broadcast ds_read_b128 + 16 fma.
// W streamed per-lane as float4 straight from global (rows are contiguous).
// FLAGS: 1 = SiLU epilogue, 2 = partial mode (no bias; C += z*part_stride).
// ---------------------------------------------------------------------------
template<int FLAGS>
__global__ __launch_bounds__(256) void k_gemvT(
    const float* __restrict__ A, int a_rs, int a_bs,
    const float* __restrict__ W, int w_rs, int w_bs,
    const float* __restrict__ bias, int bias_bs,
    float* __restrict__ C, int c_rs, int c_bs, int part_stride,
    int N, int K){
  __shared__ float As[4][64][16];   // [wave][k-local][m]
  __shared__ float Ps[4][16][64];   // [wave][m][n-lane]
  const int bb = blockIdx.y;
  const int tid = threadIdx.x, wave = tid >> 6, lane = tid & 63;
  const int n0 = blockIdx.x * 64;
  const int n  = n0 + lane;
  const int Kb = K / gridDim.z;          // this block's k-extent
  const int kseg = Kb >> 2;              // per-wave k-extent (multiple of 64)
  const int k0 = blockIdx.z * Kb + wave * kseg;
  const float* Ab = A + (size_t)bb * a_bs;
  const float* Wrow = W + (size_t)bb * w_bs + (size_t)n * w_rs;

  float acc[16];
#pragma unroll
  for (int m = 0; m < 16; ++m) acc[m] = 0.f;

  const int sm = lane >> 2;              // staging: this lane's m row
  const int sq = (lane & 3) * 4;         // staging: k-quad offset

  for (int kt = 0; kt < kseg; kt += 64){
    const int kk = k0 + kt;
    // stage A-tile [64k][16m] (wave-private; in-order wave => no barrier)
    {
      const float* Arow = Ab + (size_t)sm * a_rs + kk + sq;
#pragma unroll
      for (int r = 0; r < 4; ++r){
        float4 v = *(const float4*)(Arow + r * 16);
        int kl = sq + r * 16;
        As[wave][kl + 0][sm] = v.x;
        As[wave][kl + 1][sm] = v.y;
        As[wave][kl + 2][sm] = v.z;
        As[wave][kl + 3][sm] = v.w;
      }
    }
#pragma unroll 4
    for (int kq = 0; kq < 64; kq += 4){
      float4 wv = *(const float4*)(Wrow + kk + kq);
      float wl[4] = {wv.x, wv.y, wv.z, wv.w};
#pragma unroll
      for (int j = 0; j < 4; ++j){
        const float* ap = &As[wave][kq + j][0];
        float4 a0 = *(const float4*)(ap + 0);
        float4 a1 = *(const float4*)(ap + 4);
        float4 a2 = *(const float4*)(ap + 8);
        float4 a3 = *(const float4*)(ap + 12);
        float wj = wl[j];
        acc[ 0] = fmaf(wj, a0.x, acc[ 0]);
        acc[ 1] = fmaf(wj, a0.y, acc[ 1]);
        acc[ 2] = fmaf(wj, a0.z, acc[ 2]);
        acc[ 3] = fmaf(wj, a0.w, acc[ 3]);
        acc[ 4] = fmaf(wj, a1.x, acc[ 4]);
        acc[ 5] = fmaf(wj, a1.y, acc[ 5]);
        acc[ 6] = fmaf(wj, a1.z, acc[ 6]);
        acc[ 7] = fmaf(wj, a1.w, acc[ 7]);
        acc[ 8] = fmaf(wj, a2.x, acc[ 8]);
        acc[ 9] = fmaf(wj, a2.y, acc[ 9]);
        acc[10] = fmaf(wj, a2.z, acc[10]);
        acc[11] = fmaf(wj, a2.w, acc[11]);
        acc[12] = fmaf(wj, a3.x, acc[12]);
        acc[13] = fmaf(wj, a3.y, acc[13]);
        acc[14] = fmaf(wj, a3.z, acc[14]);
        acc[15] = fmaf(wj, a3.w, acc[15]);
      }
    }
  }
#pragma unroll
  for (int m = 0; m < 16; ++m) Ps[wave][m][lane] = acc[m];
  __syncthreads();
  // thread t: column nl = t&63, m-group (t>>6)*4 .. +3
  const int nl = tid & 63, mg = (tid >> 6) * 4;
#pragma unroll
  for (int mm = 0; mm < 4; ++mm){
    int m = mg + mm;
    float r = Ps[0][m][nl] + Ps[1][m][nl] + Ps[2][m][nl] + Ps[3][m][nl];
    if (!(FLAGS & 2) && bias) r += bias[(size_t)bb * bias_bs + n0 + nl];
    if (FLAGS & 1) r = r / (1.f + expf(-r));
    size_t ci = (size_t)bb * c_bs + (size_t)m * c_rs + (n0 + nl);
    if (FLAGS & 2) ci += (size_t)blockIdx.z * part_stride;
    C[ci] = r;
  }
}

// Self-attention per (b,h): 513 keys (512 cached + 1 new). Mask bias is a
// constant shift -> softmax-invariant -> skipped.
__global__ __launch_bounds__(512) void k_self_attn(
    const float* __restrict__ q, const float* __restrict__ kn,
    const float* __restrict__ vn, const float* __restrict__ pk,
    const float* __restrict__ pv, float* __restrict__ out){
  __shared__ float sc[513];
  __shared__ float red1[8], red2[8];
  __shared__ float o8[8 * 64];
  int bh = blockIdx.x, b = bh >> 4, hh = bh & 15;
  int tid = threadIdx.x, wave = tid >> 6, lane = tid & 63;
  size_t base = (size_t)b * NCACHE * DIM + hh * HDIM;
  float qd = q[b * DIM + hh * HDIM + lane] * SCALE;
  for (int j = wave; j < 513; j += 8){
    float kd = (j < NCACHE) ? pk[base + (size_t)j * DIM + lane]
                            : kn[b * DIM + hh * HDIM + lane];
    float p = wave_reduce_sum(qd * kd);
    if (lane == 0) sc[j] = p;
  }
  __syncthreads();
  float lm = -1e30f;
  for (int j = tid; j < 513; j += 512) lm = fmaxf(lm, sc[j]);
  lm = wave_reduce_max(lm);
  if (lane == 0) red1[wave] = lm;
  __syncthreads();
  float bm = red1[0];
#pragma unroll
  for (int w = 1; w < 8; ++w) bm = fmaxf(bm, red1[w]);
  float ls = 0.f;
  for (int j = tid; j < 513; j += 512){
    float e = expf(sc[j] - bm);
    sc[j] = e;
    ls += e;
  }
  ls = wave_reduce_sum(ls);
  if (lane == 0) red2[wave] = ls;
  __syncthreads();
  float tot = 0.f;
#pragma unroll
  for (int w = 0; w < 8; ++w) tot += red2[w];
  float inv = 1.f / tot;
  float acc = 0.f;
  for (int j = wave; j < 513; j += 8){
    float vd = (j < NCACHE) ? pv[base + (size_t)j * DIM + lane]
                            : vn[b * DIM + hh * HDIM + lane];
    acc += sc[j] * vd;
  }
  o8[wave * 64 + lane] = acc;
  __syncthreads();
  if (tid < 64){
    float s2 = 0.f;
#pragma unroll
    for (int w = 0; w < 8; ++w) s2 += o8[w * 64 + tid];
    out[b * DIM + hh * HDIM + tid] = s2 * inv;
  }
}

// out = LayerNorm(res + x) * w + b
__global__ __launch_bounds__(256) void k_add_ln(
    const float* __restrict__ res, const float* __restrict__ x,
    const float* __restrict__ w, const float* __restrict__ bln,
    float* __restrict__ out){
  __shared__ float r1[4], r2[4];
  int b = blockIdx.x, tid = threadIdx.x, wave = tid >> 6, lane = tid & 63;
  const float4* R = (const float4*)(res + (size_t)b * DIM);
  const float4* X = (const float4*)(x + (size_t)b * DIM);
  float4 rv = R[tid], xv = X[tid];
  float v0 = rv.x + xv.x, v1 = rv.y + xv.y, v2 = rv.z + xv.z, v3 = rv.w + xv.w;
  float s = v0 + v1 + v2 + v3;
  float sq = v0 * v0 + v1 * v1 + v2 * v2 + v3 * v3;
  s = wave_reduce_sum(s); sq = wave_reduce_sum(sq);
  if (lane == 0){ r1[wave] = s; r2[wave] = sq; }
  __syncthreads();
  float ts = r1[0] + r1[1] + r1[2] + r1[3];
  float tq = r2[0] + r2[1] + r2[2] + r2[3];
  float mean = ts * (1.f / DIM);
  float var = tq * (1.f / DIM) - mean * mean;
  float rstd = rsqrtf(var + 1e-5f);
  const float4* W4 = (const float4*)w;
  const float4* B4 = (const float4*)bln;
  float4 wv = W4[tid], bv = B4[tid];
  float4 o;
  o.x = (v0 - mean) * rstd * wv.x + bv.x;
  o.y = (v1 - mean) * rstd * wv.y + bv.y;
  o.z = (v2 - mean) * rstd * wv.z + bv.z;
  o.w = (v3 - mean) * rstd * wv.w + bv.w;
  ((float4*)(out + (size_t)b * DIM))[tid] = o;
}

// out = LayerNorm(res + P0+P1+P2+P3 + fcb) * w + b   (fc2 partials)
__global__ __launch_bounds__(256) void k_add_ln_p4(
    const float* __restrict__ res, const float* __restrict__ P,
    const float* __restrict__ fcb, const float* __restrict__ w,
    const float* __restrict__ bln, float* __restrict__ out){
  __shared__ float r1[4], r2[4];
  int b = blockIdx.x, tid = threadIdx.x, wave = tid >> 6, lane = tid & 63;
  const float4* R = (const float4*)(res + (size_t)b * DIM);
  float4 rv = R[tid];
  const float4* F = (const float4*)fcb;
  float4 fv = F[tid];
  float v0 = rv.x + fv.x, v1 = rv.y + fv.y, v2 = rv.z + fv.z, v3 = rv.w + fv.w;
#pragma unroll
  for (int z = 0; z < 4; ++z){
    const float4* Pz = (const float4*)(P + (size_t)z * 16384 + (size_t)b * DIM);
    float4 pv = Pz[tid];
    v0 += pv.x; v1 += pv.y; v2 += pv.z; v3 += pv.w;
  }
  float s = v0 + v1 + v2 + v3;
  float sq = v0 * v0 + v1 * v1 + v2 * v2 + v3 * v3;
  s = wave_reduce_sum(s); sq = wave_reduce_sum(sq);
  if (lane == 0){ r1[wave] = s; r2[wave] = sq; }
  __syncthreads();
  float ts = r1[0] + r1[1] + r1[2] + r1[3];
  float tq = r2[0] + r2[1] + r2[2] + r2[3];
  float mean = ts * (1.f / DIM);
  float var = tq * (1.f / DIM) - mean * mean;
  float rstd = rsqrtf(var + 1e-5f);
  const float4* W4 = (const float4*)w;
  const float4* B4 = (const float4*)bln;
  float4 wv = W4[tid], bv = B4[tid];
  float4 o;
  o.x = (v0 - mean) * rstd * wv.x + bv.x;
  o.y = (v1 - mean) * rstd * wv.y + bv.y;
  o.z = (v2 - mean) * rstd * wv.z + bv.z;
  o.w = (v3 - mean) * rstd * wv.w + bv.w;
  ((float4*)(out + (size_t)b * DIM))[tid] = o;
}

// g[b][h][c] = sum_d (q[b][h*64+d]*SCALE) * kw[h*64+d][c]
__global__ __launch_bounds__(256) void k_gmat(const float* __restrict__ q,
                                              const float* __restrict__ kw,
                                              float* __restrict__ g){
  __shared__ float ql[16 * 64];
  int hh = blockIdx.y;
  int c = blockIdx.x * 256 + threadIdx.x;
  for (int i = threadIdx.x; i < 16 * 64; i += 256){
    int b = i >> 6, d = i & 63;
    ql[i] = q[b * DIM + hh * HDIM + d] * SCALE;
  }
  __syncthreads();
  float acc[16];
#pragma unroll
  for (int m = 0; m < 16; ++m) acc[m] = 0.f;
  for (int d = 0; d < 64; ++d){
    float wv = kw[(size_t)(hh * HDIM + d) * DIM + c];
#pragma unroll
    for (int b = 0; b < 16; ++b) acc[b] = fmaf(ql[b * 64 + d], wv, acc[b]);
  }
#pragma unroll
  for (int b = 0; b < 16; ++b) g[(size_t)(b * NH + hh) * DIM + c] = acc[b];
}

// In-place softmax over rows of 512
__global__ __launch_bounds__(512) void k_softmax512(float* __restrict__ s){
  __shared__ float red[8];
  float* row = s + (size_t)blockIdx.x * SRCLEN;
  int tid = threadIdx.x, wave = tid >> 6, lane = tid & 63;
  float v = row[tid];
  float m = wave_reduce_max(v);
  if (lane == 0) red[wave] = m;
  __syncthreads();
  float bm = red[0];
#pragma unroll
  for (int w = 1; w < 8; ++w) bm = fmaxf(bm, red[w]);
  float e = expf(v - bm);
  __syncthreads();
  float ls = wave_reduce_sum(e);
  if (lane == 0) red[wave] = ls;
  __syncthreads();
  float tot = 0.f;
#pragma unroll
  for (int w = 0; w < 8; ++w) tot += red[w];
  row[tid] = e / tot;
}

extern "C" void kernel_launch(void* const* d_in, const int* in_sizes, int n_in,
                              void* d_out, int out_size, void* d_ws, size_t ws_size,
                              hipStream_t stream){
  const float* de   = (const float*)d_in[0];
  const float* enc  = (const float*)d_in[1];
  const float* pk   = (const float*)d_in[2];
  const float* pv   = (const float*)d_in[3];
  const int*   cl   = (const int*)d_in[4];
  const float* pe   = (const float*)d_in[5];
  const float* saqw = (const float*)d_in[6];
  const float* sakw = (const float*)d_in[7];
  const float* savw = (const float*)d_in[8];
  const float* saow = (const float*)d_in[9];
  const float* caqw = (const float*)d_in[10];
  const float* cakw = (const float*)d_in[11];
  const float* cavw = (const float*)d_in[12];
  const float* caow = (const float*)d_in[13];
  const float* saqb = (const float*)d_in[14];
  const float* sakb = (const float*)d_in[15];
  const float* savb = (const float*)d_in[16];
  const float* saob = (const float*)d_in[17];
  const float* caqb = (const float*)d_in[18];
  const float* cakb = (const float*)d_in[19];
  const float* cavb = (const float*)d_in[20];
  const float* caob = (const float*)d_in[21];
  const float* fc1w = (const float*)d_in[22];
  const float* fc1b = (const float*)d_in[23];
  const float* fc2w = (const float*)d_in[24];
  const float* fc2b = (const float*)d_in[25];
  const float* ln1w = (const float*)d_in[26];
  const float* ln2w = (const float*)d_in[27];
  const float* ln3w = (const float*)d_in[28];
  const float* ln1b = (const float*)d_in[29];
  const float* ln2b = (const float*)d_in[30];
  const float* ln3b = (const float*)d_in[31];
  const float* lmw  = (const float*)d_in[32];
  float* out = (float*)d_out;
  float* ws  = (float*)d_ws;

  float* h    = ws;             // [16][1024]
  float* qb   = ws + 16384;     // [16][1024]
  float* attn = ws + 65536;     // [16][1024]
  float* tmp  = ws + 81920;     // [16][4096] fc1 out
  float* tmp2 = ws + 147456;    // [16][1024]
  float* g    = ws + 163840;    // [16][16][1024]
  float* s    = ws + 425984;    // [16][16][512]
  float* ctx  = ws + 557056;    // [16][16][1024]
  float* encT = ws + 819200;    // [16][1024][512]
  float* Pfc  = ws + 9207808;   // [4][16][1024] fc2 partials

  float* out_k = out + 512000;  // [L][16][1024]
  float* out_v = out + 610304;  // [L][16][1024]

  k_transpose<<<dim3(16, 8, 16), dim3(64, 4), 0, stream>>>(enc, encT);
  k_embed<<<16, 256, 0, stream>>>(de, pe, cl, h);

  for (int i = 0; i < LYRS; ++i){
    size_t wo = (size_t)i * DIM * DIM;
    size_t bo = (size_t)i * DIM;
    float* ko = out_k + (size_t)i * BATCH * DIM;
    float* vo = out_v + (size_t)i * BATCH * DIM;
    // ---- self-attention ----
    k_gemvT<0><<<dim3(16, 1, 1), 256, 0, stream>>>(h, DIM, 0, saqw + wo, DIM, 0,
        saqb + bo, 0, qb, DIM, 0, 0, DIM, DIM);
    k_gemvT<0><<<dim3(16, 1, 1), 256, 0, stream>>>(h, DIM, 0, sakw + wo, DIM, 0,
        sakb + bo, 0, ko, DIM, 0, 0, DIM, DIM);
    k_gemvT<0><<<dim3(16, 1, 1), 256, 0, stream>>>(h, DIM, 0, savw + wo, DIM, 0,
        savb + bo, 0, vo, DIM, 0, 0, DIM, DIM);
    k_self_attn<<<256, 512, 0, stream>>>(qb, ko, vo,
        pk + (size_t)i * BATCH * NCACHE * DIM, pv + (size_t)i * BATCH * NCACHE * DIM, attn);
    k_gemvT<0><<<dim3(16, 1, 1), 256, 0, stream>>>(attn, DIM, 0, saow + wo, DIM, 0,
        saob + bo, 0, tmp2, DIM, 0, 0, DIM, DIM);
    k_add_ln<<<16, 256, 0, stream>>>(h, tmp2, ln1w + bo, ln1b + bo, h);
    // ---- cross-attention (K/V projections folded around the softmax) ----
    k_gemvT<0><<<dim3(16, 1, 1), 256, 0, stream>>>(h, DIM, 0, caqw + wo, DIM, 0,
        caqb + bo, 0, qb, DIM, 0, 0, DIM, DIM);
    k_gmat<<<dim3(4, 16), 256, 0, stream>>>(qb, cakw + wo, g);
    // scores: s[b][h][j] = sum_d g[b][h][d] * enc[b][j][d]
    k_gemvT<0><<<dim3(8, 16, 1), 256, 0, stream>>>(g, DIM, NH * DIM,
        enc, DIM, SRCLEN * DIM, nullptr, 0,
        s, SRCLEN, NH * SRCLEN, 0, SRCLEN, DIM);
    k_softmax512<<<256, 512, 0, stream>>>(s);
    // ctx: ctx[b][h][c] = sum_j p[b][h][j] * encT[b][c][j]
    k_gemvT<0><<<dim3(16, 16, 1), 256, 0, stream>>>(s, SRCLEN, NH * SRCLEN,
        encT, SRCLEN, DIM * SRCLEN, nullptr, 0,
        ctx, DIM, NH * DIM, 0, DIM, SRCLEN);
    // vout (batched over h): attn[b][h*64+c] = sum_d ctx[b][h][d]*cavw[h*64+c][d]+cavb
    k_gemvT<0><<<dim3(1, 16, 1), 256, 0, stream>>>(ctx, NH * DIM, DIM,
        cavw + wo, DIM, HDIM * DIM, cavb + bo, HDIM,
        attn, DIM, HDIM, 0, HDIM, DIM);
    k_gemvT<0><<<dim3(16, 1, 1), 256, 0, stream>>>(attn, DIM, 0, caow + wo, DIM, 0,
        caob + bo, 0, tmp2, DIM, 0, 0, DIM, DIM);
    k_add_ln<<<16, 256, 0, stream>>>(h, tmp2, ln2w + bo, ln2b + bo, h);
    // ---- FFN ----
    k_gemvT<1><<<dim3(64, 1, 1), 256, 0, stream>>>(h, DIM, 0,
        fc1w + (size_t)i * FFNDIM * DIM, DIM, 0, fc1b + (size_t)i * FFNDIM, 0,
        tmp, FFNDIM, 0, 0, FFNDIM, DIM);
    k_gemvT<2><<<dim3(16, 1, 4), 256, 0, stream>>>(tmp, FFNDIM, 0,
        fc2w + (size_t)i * DIM * FFNDIM, FFNDIM, 0, nullptr, 0,
        Pfc, DIM, 0, BATCH * DIM, DIM, FFNDIM);
    k_add_ln_p4<<<16, 256, 0, stream>>>(h, Pfc, fc2b + bo, ln3w + bo, ln3b + bo, h);
  }
  // ---- lm_head ----
  k_gemvT<0><<<dim3(VOCAB / 64, 1, 1), 256, 0, stream>>>(h, DIM, 0, lmw, DIM, 0,
      nullptr, 0, out, VOCAB, 0, 0, VOCAB, DIM);
}

// Round 3
// 1424.220 us; speedup vs baseline: 1.8191x; 1.3040x over previous
//
#include <hip/hip_runtime.h>
#include <math.h>

#define LYRS 6
#define BATCH 16
#define DIM 1024
#define NH 16
#define HDIM 64
#define FFNDIM 4096
#define VOCAB 32000
#define NCACHE 512
#define SRCLEN 512
#define SCALE 0.125f
#define EMB_SCALE 32.0f

__device__ __forceinline__ float wave_reduce_sum(float v){
#pragma unroll
  for (int off = 32; off; off >>= 1) v += __shfl_xor(v, off, 64);
  return v;
}
__device__ __forceinline__ float wave_reduce_max(float v){
#pragma unroll
  for (int off = 32; off; off >>= 1) v = fmaxf(v, __shfl_xor(v, off, 64));
  return v;
}

// h[b][d] = decoder_embed[b][d]*sqrt(D) + pe[cache_len][d]
__global__ __launch_bounds__(256) void k_embed(const float* __restrict__ de,
                                               const float* __restrict__ pe,
                                               const int* __restrict__ cl,
                                               float* __restrict__ h){
  int b = blockIdx.x, t = threadIdx.x;
  int c = cl[0];
  const float4* d4 = (const float4*)(de + (size_t)b * DIM);
  const float4* p4 = (const float4*)(pe + (size_t)c * DIM);
  float4* h4 = (float4*)(h + (size_t)b * DIM);
  float4 a = d4[t], p = p4[t];
  float4 o;
  o.x = a.x * EMB_SCALE + p.x; o.y = a.y * EMB_SCALE + p.y;
  o.z = a.z * EMB_SCALE + p.z; o.w = a.w * EMB_SCALE + p.w;
  h4[t] = o;
}

// ---------------------------------------------------------------------------
// GEMV core: C_partial[m][n] = sum_{k in this block's chunk} A[m][k]*W[n][k]
// A read via wave-uniform scalar loads (SMEM pipe), W streamed per-lane float4.
// 4 waves split the block's K-chunk; Ps LDS combine; partial written (no bias).
// ---------------------------------------------------------------------------
template<int KSEG>
__device__ __forceinline__ void gemv_body(
    const float* __restrict__ Ab, int a_rs,
    const float* __restrict__ Wb, int w_rs,
    float* __restrict__ Cz, int c_rs, int n0){
  __shared__ float Ps[4][16][64];
  const int tid = threadIdx.x, lane = tid & 63;
  const int wave = __builtin_amdgcn_readfirstlane(tid >> 6);
  const int k0 = blockIdx.z * (KSEG * 4) + wave * KSEG;
  const float* Wn = Wb + (size_t)(n0 + lane) * w_rs + k0;
  const float* An = Ab + k0;
  float acc[16];
#pragma unroll
  for (int m = 0; m < 16; ++m) acc[m] = 0.f;
  constexpr int CH = (KSEG >= 64) ? 64 : KSEG;
  for (int g = 0; g < KSEG; g += CH){
    float4 wv[CH / 4];
#pragma unroll
    for (int c = 0; c < CH / 4; ++c) wv[c] = *(const float4*)(Wn + g + c * 4);
#pragma unroll
    for (int c = 0; c < CH / 4; ++c){
      const float* ap = An + g + c * 4;
      float wl0 = wv[c].x, wl1 = wv[c].y, wl2 = wv[c].z, wl3 = wv[c].w;
#pragma unroll
      for (int m = 0; m < 16; ++m){
        const float* am = ap + (size_t)m * a_rs;
        acc[m] = fmaf(wl0, am[0], acc[m]);
        acc[m] = fmaf(wl1, am[1], acc[m]);
        acc[m] = fmaf(wl2, am[2], acc[m]);
        acc[m] = fmaf(wl3, am[3], acc[m]);
      }
    }
  }
#pragma unroll
  for (int m = 0; m < 16; ++m) Ps[wave][m][lane] = acc[m];
  __syncthreads();
  const int nl = tid & 63, mg = (tid >> 6) * 4;
#pragma unroll
  for (int mm = 0; mm < 4; ++mm){
    int m = mg + mm;
    float r = Ps[0][m][nl] + Ps[1][m][nl] + Ps[2][m][nl] + Ps[3][m][nl];
    Cz[(size_t)m * c_rs + n0 + nl] = r;
  }
}

template<int KSEG>
__global__ __launch_bounds__(256) void k_gemv(
    const float* __restrict__ A, int a_rs, int a_bs,
    const float* __restrict__ W, int w_rs, int w_bs,
    float* __restrict__ C, int c_rs, int c_bs, int c_zs){
  const int bb = blockIdx.y;
  gemv_body<KSEG>(A + (size_t)bb * a_bs, a_rs,
                  W + (size_t)bb * w_bs, w_rs,
                  C + (size_t)blockIdx.z * c_zs + (size_t)bb * c_bs, c_rs,
                  blockIdx.x * 64);
}

// QKV fused: blockIdx.y selects one of 3 weight matrices / output slabs.
template<int KSEG>
__global__ __launch_bounds__(256) void k_gemv3(
    const float* __restrict__ A,
    const float* __restrict__ W0, const float* __restrict__ W1,
    const float* __restrict__ W2, float* __restrict__ C){
  const int y = blockIdx.y;
  const float* W = (y == 0) ? W0 : ((y == 1) ? W1 : W2);
  gemv_body<KSEG>(A, DIM, W, DIM,
                  C + ((size_t)y * 16 + blockIdx.z) * (BATCH * DIM), DIM,
                  blockIdx.x * 64);
}

// Finisher: out[i] = (sum_z P[z][i] + bias[i & bmask]) [silu] [scale]
template<int NZ, bool SILU, bool DOSCALE>
__global__ __launch_bounds__(256) void k_fin(const float* __restrict__ P, int zs,
    const float* __restrict__ bias, int bmask, float* __restrict__ out){
  int i = blockIdx.x * 256 + threadIdx.x;
  float r = bias[i & bmask];
#pragma unroll
  for (int z = 0; z < NZ; ++z) r += P[(size_t)z * zs + i];
  if (SILU) r = r / (1.f + expf(-r));
  if (DOSCALE) r *= SCALE;
  out[i] = r;
}

// Self-attention per (b,h): sums the 16 QKV k-split partials (+bias), writes
// new k/v to d_out, attends over 513 keys. Mask bias is softmax-invariant.
__global__ __launch_bounds__(512) void k_self_attn(
    const float* __restrict__ Pqkv, const float* __restrict__ qb_,
    const float* __restrict__ kb_, const float* __restrict__ vb_,
    const float* __restrict__ pk, const float* __restrict__ pv,
    float* __restrict__ satt, float* __restrict__ out_k,
    float* __restrict__ out_v){
  __shared__ float sc[513];
  __shared__ float red1[8], red2[8];
  __shared__ float o8[8 * 64];
  int bh = blockIdx.x, b = bh >> 4, hh = bh & 15;
  int tid = threadIdx.x, wave = tid >> 6, lane = tid & 63;
  int hd = hh * HDIM + lane;
  const float* Pq = Pqkv;
  const float* Pk = Pqkv + 16 * BATCH * DIM;
  const float* Pv = Pqkv + 32 * BATCH * DIM;
  float qd = qb_[hd], kd = kb_[hd], vd = vb_[hd];
#pragma unroll
  for (int z = 0; z < 16; ++z){
    size_t o = (size_t)z * (BATCH * DIM) + b * DIM + hd;
    qd += Pq[o]; kd += Pk[o]; vd += Pv[o];
  }
  if (tid < 64){ out_k[b * DIM + hd] = kd; out_v[b * DIM + hd] = vd; }
  qd *= SCALE;
  size_t base = (size_t)b * NCACHE * DIM + hh * HDIM;
  for (int j = wave; j < 513; j += 8){
    float kj = (j < NCACHE) ? pk[base + (size_t)j * DIM + lane] : kd;
    float p = wave_reduce_sum(qd * kj);
    if (lane == 0) sc[j] = p;
  }
  __syncthreads();
  float lm = -1e30f;
  for (int j = tid; j < 513; j += 512) lm = fmaxf(lm, sc[j]);
  lm = wave_reduce_max(lm);
  if (lane == 0) red1[wave] = lm;
  __syncthreads();
  float bm = red1[0];
#pragma unroll
  for (int w = 1; w < 8; ++w) bm = fmaxf(bm, red1[w]);
  float ls = 0.f;
  for (int j = tid; j < 513; j += 512){
    float e = expf(sc[j] - bm);
    sc[j] = e;
    ls += e;
  }
  ls = wave_reduce_sum(ls);
  if (lane == 0) red2[wave] = ls;
  __syncthreads();
  float tot = 0.f;
#pragma unroll
  for (int w = 0; w < 8; ++w) tot += red2[w];
  float inv = 1.f / tot;
  float acc = 0.f;
  for (int j = wave; j < 513; j += 8){
    float vj = (j < NCACHE) ? pv[base + (size_t)j * DIM + lane] : vd;
    acc += sc[j] * vj;
  }
  o8[wave * 64 + lane] = acc;
  __syncthreads();
  if (tid < 64){
    float s2 = 0.f;
#pragma unroll
    for (int w = 0; w < 8; ++w) s2 += o8[w * 64 + tid];
    satt[b * DIM + hh * HDIM + tid] = s2 * inv;
  }
}

// h = LayerNorm(res + sum_z P[z] + obias) * w + b   (in-place safe per-thread)
template<int NZ>
__global__ __launch_bounds__(256) void k_add_ln_pz(
    const float* __restrict__ res, const float* __restrict__ P, int zs,
    const float* __restrict__ obias, const float* __restrict__ w,
    const float* __restrict__ bln, float* __restrict__ outh){
  __shared__ float r1[4], r2[4];
  int b = blockIdx.x, tid = threadIdx.x, wave = tid >> 6, lane = tid & 63;
  float4 rv = ((const float4*)(res + (size_t)b * DIM))[tid];
  float4 ob = ((const float4*)obias)[tid];
  float v0 = rv.x + ob.x, v1 = rv.y + ob.y, v2 = rv.z + ob.z, v3 = rv.w + ob.w;
#pragma unroll
  for (int z = 0; z < NZ; ++z){
    float4 pz = ((const float4*)(P + (size_t)z * zs + (size_t)b * DIM))[tid];
    v0 += pz.x; v1 += pz.y; v2 += pz.z; v3 += pz.w;
  }
  float s = v0 + v1 + v2 + v3;
  float sq = v0 * v0 + v1 * v1 + v2 * v2 + v3 * v3;
  s = wave_reduce_sum(s); sq = wave_reduce_sum(sq);
  if (lane == 0){ r1[wave] = s; r2[wave] = sq; }
  __syncthreads();
  float ts = r1[0] + r1[1] + r1[2] + r1[3];
  float tq = r2[0] + r2[1] + r2[2] + r2[3];
  float mean = ts * (1.f / DIM);
  float var = tq * (1.f / DIM) - mean * mean;
  float rstd = rsqrtf(var + 1e-5f);
  float4 wv = ((const float4*)w)[tid], bv = ((const float4*)bln)[tid];
  float4 o;
  o.x = (v0 - mean) * rstd * wv.x + bv.x;
  o.y = (v1 - mean) * rstd * wv.y + bv.y;
  o.z = (v2 - mean) * rstd * wv.z + bv.z;
  o.w = (v3 - mean) * rstd * wv.w + bv.w;
  ((float4*)(outh + (size_t)b * DIM))[tid] = o;
}

// g[b][h][c] = sum_d qv[b][h*64+d] * kw[h*64+d][c]   (qv pre-scaled)
__global__ __launch_bounds__(256) void k_gmat2(const float* __restrict__ qv,
                                               const float* __restrict__ kw,
                                               float* __restrict__ g){
  __shared__ float Ps[4][16][64];
  const int hh = blockIdx.y, c0 = blockIdx.x * 64;
  const int tid = threadIdx.x, lane = tid & 63;
  const int wave = __builtin_amdgcn_readfirstlane(tid >> 6);
  float acc[16];
#pragma unroll
  for (int m = 0; m < 16; ++m) acc[m] = 0.f;
#pragma unroll
  for (int dd = 0; dd < 16; ++dd){
    int hd = hh * HDIM + wave * 16 + dd;
    float kwv = kw[(size_t)hd * DIM + c0 + lane];
#pragma unroll
    for (int b = 0; b < 16; ++b)
      acc[b] = fmaf(qv[b * DIM + hd], kwv, acc[b]);
  }
#pragma unroll
  for (int m = 0; m < 16; ++m) Ps[wave][m][lane] = acc[m];
  __syncthreads();
  const int nl = tid & 63, mg = (tid >> 6) * 4;
#pragma unroll
  for (int mm = 0; mm < 4; ++mm){
    int m = mg + mm;
    float r = Ps[0][m][nl] + Ps[1][m][nl] + Ps[2][m][nl] + Ps[3][m][nl];
    g[((size_t)m * NH + hh) * DIM + c0 + nl] = r;
  }
}

// softmax over rows of 512, input = sum of 2 k-split partials
__global__ __launch_bounds__(512) void k_softmax512p(const float* __restrict__ S,
                                                     float* __restrict__ p){
  __shared__ float red[8];
  int row = blockIdx.x;
  int tid = threadIdx.x, wave = tid >> 6, lane = tid & 63;
  float v = S[(size_t)row * SRCLEN + tid] +
            S[(size_t)BATCH * NH * SRCLEN + (size_t)row * SRCLEN + tid];
  float m = wave_reduce_max(v);
  if (lane == 0) red[wave] = m;
  __syncthreads();
  float bm = red[0];
#pragma unroll
  for (int w = 1; w < 8; ++w) bm = fmaxf(bm, red[w]);
  float e = expf(v - bm);
  __syncthreads();
  float ls = wave_reduce_sum(e);
  if (lane == 0) red[wave] = ls;
  __syncthreads();
  float tot = 0.f;
#pragma unroll
  for (int w = 0; w < 8; ++w) tot += red[w];
  p[(size_t)row * SRCLEN + tid] = e / tot;
}

// ctx[b][h][c] = sum_j p[b][h][j] * enc[b][j][c]
__global__ __launch_bounds__(256) void k_ctx(const float* __restrict__ p,
                                             const float* __restrict__ enc,
                                             float* __restrict__ ctx){
  __shared__ float Ps[4][16][64];
  const int b = blockIdx.y, c0 = blockIdx.x * 64;
  const int tid = threadIdx.x, lane = tid & 63;
  const int wave = __builtin_amdgcn_readfirstlane(tid >> 6);
  const float* pb = p + (size_t)b * NH * SRCLEN;
  const float* eb = enc + (size_t)b * SRCLEN * DIM + c0 + lane;
  float acc[16];
#pragma unroll
  for (int m = 0; m < 16; ++m) acc[m] = 0.f;
  for (int jj = 0; jj < 128; ++jj){
    int j = wave * 128 + jj;
    float ev = eb[(size_t)j * DIM];
#pragma unroll
    for (int h = 0; h < 16; ++h)
      acc[h] = fmaf(pb[h * SRCLEN + j], ev, acc[h]);
  }
#pragma unroll
  for (int m = 0; m < 16; ++m) Ps[wave][m][lane] = acc[m];
  __syncthreads();
  const int nl = tid & 63, mg = (tid >> 6) * 4;
#pragma unroll
  for (int mm = 0; mm < 4; ++mm){
    int m = mg + mm;
    float r = Ps[0][m][nl] + Ps[1][m][nl] + Ps[2][m][nl] + Ps[3][m][nl];
    ctx[((size_t)b * NH + m) * DIM + c0 + nl] = r;
  }
}

extern "C" void kernel_launch(void* const* d_in, const int* in_sizes, int n_in,
                              void* d_out, int out_size, void* d_ws, size_t ws_size,
                              hipStream_t stream){
  const float* de   = (const float*)d_in[0];
  const float* enc  = (const float*)d_in[1];
  const float* pk   = (const float*)d_in[2];
  const float* pv   = (const float*)d_in[3];
  const int*   cl   = (const int*)d_in[4];
  const float* pe   = (const float*)d_in[5];
  const float* saqw = (const float*)d_in[6];
  const float* sakw = (const float*)d_in[7];
  const float* savw = (const float*)d_in[8];
  const float* saow = (const float*)d_in[9];
  const float* caqw = (const float*)d_in[10];
  const float* cakw = (const float*)d_in[11];
  const float* cavw = (const float*)d_in[12];
  const float* caow = (const float*)d_in[13];
  const float* saqb = (const float*)d_in[14];
  const float* sakb = (const float*)d_in[15];
  const float* savb = (const float*)d_in[16];
  const float* saob = (const float*)d_in[17];
  const float* caqb = (const float*)d_in[18];
  const float* cakb = (const float*)d_in[19];
  const float* cavb = (const float*)d_in[20];
  const float* caob = (const float*)d_in[21];
  const float* fc1w = (const float*)d_in[22];
  const float* fc1b = (const float*)d_in[23];
  const float* fc2w = (const float*)d_in[24];
  const float* fc2b = (const float*)d_in[25];
  const float* ln1w = (const float*)d_in[26];
  const float* ln2w = (const float*)d_in[27];
  const float* ln3w = (const float*)d_in[28];
  const float* ln1b = (const float*)d_in[29];
  const float* ln2b = (const float*)d_in[30];
  const float* ln3b = (const float*)d_in[31];
  const float* lmw  = (const float*)d_in[32];
  float* out = (float*)d_out;
  float* ws  = (float*)d_ws;

  float* h    = ws;              // [16][1024]
  float* satt = ws + 16384;      // [16][1024]
  float* catt = ws + 32768;      // [16][1024]
  float* qv   = ws + 49152;      // [16][1024]
  float* tmp  = ws + 65536;      // [16][4096]
  float* g    = ws + 131072;     // [16][16][1024]
  float* p    = ws + 393216;     // [16][16][512]
  float* ctx  = ws + 524288;     // [16][16][1024]
  float* Pqkv = ws + 786432;     // [3][16][16][1024]
  float* Po   = ws + 1572864;    // [16][16][1024]
  float* Pcq  = ws + 1835008;    // [16][16][1024]
  float* Pvo  = ws + 2097152;    // [16][16][1024]
  float* Pco  = ws + 2359296;    // [16][16][1024]
  float* Pf1  = ws + 2621440;    // [4][16][4096]
  float* Pf2  = ws + 2883584;    // [16][16][1024]
  float* s2   = ws + 3145728;    // [2][16][16][512]

  float* out_k = out + 512000;   // [L][16][1024]
  float* out_v = out + 610304;   // [L][16][1024]

  k_embed<<<16, 256, 0, stream>>>(de, pe, cl, h);

  for (int i = 0; i < LYRS; ++i){
    size_t wo = (size_t)i * DIM * DIM;
    size_t bo = (size_t)i * DIM;
    float* ko = out_k + (size_t)i * BATCH * DIM;
    float* vo = out_v + (size_t)i * BATCH * DIM;
    // ---- self-attention ----
    k_gemv3<16><<<dim3(16, 3, 16), 256, 0, stream>>>(h, saqw + wo, sakw + wo,
        savw + wo, Pqkv);
    k_self_attn<<<256, 512, 0, stream>>>(Pqkv, saqb + bo, sakb + bo, savb + bo,
        pk + (size_t)i * BATCH * NCACHE * DIM, pv + (size_t)i * BATCH * NCACHE * DIM,
        satt, ko, vo);
    k_gemv<16><<<dim3(16, 1, 16), 256, 0, stream>>>(satt, DIM, 0,
        saow + wo, DIM, 0, Po, DIM, 0, BATCH * DIM);
    k_add_ln_pz<16><<<16, 256, 0, stream>>>(h, Po, BATCH * DIM, saob + bo,
        ln1w + bo, ln1b + bo, h);
    // ---- cross-attention (K/V projections folded around the softmax) ----
    k_gemv<16><<<dim3(16, 1, 16), 256, 0, stream>>>(h, DIM, 0,
        caqw + wo, DIM, 0, Pcq, DIM, 0, BATCH * DIM);
    k_fin<16, false, true><<<64, 256, 0, stream>>>(Pcq, BATCH * DIM,
        caqb + bo, DIM - 1, qv);
    k_gmat2<<<dim3(16, 16), 256, 0, stream>>>(qv, cakw + wo, g);
    k_gemv<128><<<dim3(8, 16, 2), 256, 0, stream>>>(g, DIM, NH * DIM,
        enc, DIM, SRCLEN * DIM, s2, SRCLEN, NH * SRCLEN, BATCH * NH * SRCLEN);
    k_softmax512p<<<256, 512, 0, stream>>>(s2, p);
    k_ctx<<<dim3(16, 16), 256, 0, stream>>>(p, enc, ctx);
    k_gemv<16><<<dim3(1, 16, 16), 256, 0, stream>>>(ctx, NH * DIM, DIM,
        cavw + wo, DIM, HDIM * DIM, Pvo, DIM, HDIM, BATCH * DIM);
    k_fin<16, false, false><<<64, 256, 0, stream>>>(Pvo, BATCH * DIM,
        cavb + bo, DIM - 1, catt);
    k_gemv<16><<<dim3(16, 1, 16), 256, 0, stream>>>(catt, DIM, 0,
        caow + wo, DIM, 0, Pco, DIM, 0, BATCH * DIM);
    k_add_ln_pz<16><<<16, 256, 0, stream>>>(h, Pco, BATCH * DIM, caob + bo,
        ln2w + bo, ln2b + bo, h);
    // ---- FFN ----
    k_gemv<64><<<dim3(64, 1, 4), 256, 0, stream>>>(h, DIM, 0,
        fc1w + (size_t)i * FFNDIM * DIM, DIM, 0, Pf1, FFNDIM, 0, BATCH * FFNDIM);
    k_fin<4, true, false><<<256, 256, 0, stream>>>(Pf1, BATCH * FFNDIM,
        fc1b + (size_t)i * FFNDIM, FFNDIM - 1, tmp);
    k_gemv<64><<<dim3(16, 1, 16), 256, 0, stream>>>(tmp, FFNDIM, 0,
        fc2w + (size_t)i * DIM * FFNDIM, FFNDIM, 0, Pf2, DIM, 0, BATCH * DIM);
    k_add_ln_pz<16><<<16, 256, 0, stream>>>(h, Pf2, BATCH * DIM, fc2b + bo,
        ln3w + bo, ln3b + bo, h);
  }
  // ---- lm_head ----
  k_gemv<256><<<dim3(VOCAB / 64, 1, 1), 256, 0, stream>>>(h, DIM, 0,
      lmw, DIM, 0, out, VOCAB, 0, 0);
}

// Round 4
// 827.564 us; speedup vs baseline: 3.1306x; 1.7210x over previous
//
#include <hip/hip_runtime.h>
#include <math.h>

#define LYRS 6
#define BATCH 16
#define DIM 1024
#define NH 16
#define HDIM 64
#define FFNDIM 4096
#define VOCAB 32000
#define NCACHE 512
#define SRCLEN 512
#define SCALE 0.125f
#define EMB_SCALE 32.0f

__device__ __forceinline__ float wave_reduce_sum(float v){
#pragma unroll
  for (int off = 32; off; off >>= 1) v += __shfl_xor(v, off, 64);
  return v;
}
__device__ __forceinline__ float wave_reduce_max(float v){
#pragma unroll
  for (int off = 32; off; off >>= 1) v = fmaxf(v, __shfl_xor(v, off, 64));
  return v;
}
__device__ __forceinline__ float4 silu4(float4 v){
  v.x = v.x / (1.f + expf(-v.x));
  v.y = v.y / (1.f + expf(-v.y));
  v.z = v.z / (1.f + expf(-v.z));
  v.w = v.w / (1.f + expf(-v.w));
  return v;
}

// h[b][d] = decoder_embed[b][d]*sqrt(D) + pe[cache_len][d]
__global__ __launch_bounds__(256) void k_embed(const float* __restrict__ de,
                                               const float* __restrict__ pe,
                                               const int* __restrict__ cl,
                                               float* __restrict__ h){
  int b = blockIdx.x, t = threadIdx.x;
  int c = cl[0];
  const float4* d4 = (const float4*)(de + (size_t)b * DIM);
  const float4* p4 = (const float4*)(pe + (size_t)c * DIM);
  float4* h4 = (float4*)(h + (size_t)b * DIM);
  float4 a = d4[t], p = p4[t];
  float4 o;
  o.x = a.x * EMB_SCALE + p.x; o.y = a.y * EMB_SCALE + p.y;
  o.z = a.z * EMB_SCALE + p.z; o.w = a.w * EMB_SCALE + p.w;
  h4[t] = o;
}

// ---------------------------------------------------------------------------
// m-split GEMV core. Block: 256 threads / 4 waves. Block covers n-tile of 64
// (lane-owned) and k-range [k0, k0+KPB). Waves split M (4 rows each) and
// SHARE the W stream (L2 absorbs the 4x re-read). A staged in LDS k-major;
// FMA loop reads A via broadcast ds_read_b128. Each wave writes its 4 rows
// of the z-partial directly - no cross-wave combine.
// A-staging optionally folds NZ k-split partials + a k-indexed bias + SiLU.
// ---------------------------------------------------------------------------
template<int KPB, int NZ, bool SILU>
__device__ __forceinline__ void gemv_ms_core(
    const float* __restrict__ Asrc, int a_rs, int pz,
    const float* __restrict__ abias,
    const float* __restrict__ W, int w_rs,
    float* __restrict__ Cz, int c_rs,
    int n0, int k0){
  __shared__ float As[16][KPB];
  const int tid = threadIdx.x;
  {
    const int m = tid >> 4;
    const int q0 = (tid & 15) * 4;
    constexpr int QPT = KPB / 64;
#pragma unroll
    for (int qq = 0; qq < QPT; ++qq){
      const int q = q0 + qq * 64;
      const int gk = k0 + q;
      float4 v;
      if (NZ == 0){
        v = *(const float4*)(Asrc + (size_t)m * a_rs + gk);
      } else {
        if (abias) v = *(const float4*)(abias + gk);
        else { v.x = 0.f; v.y = 0.f; v.z = 0.f; v.w = 0.f; }
#pragma unroll
        for (int z = 0; z < NZ; ++z){
          float4 pv = *(const float4*)(Asrc + (size_t)z * pz + (size_t)m * a_rs + gk);
          v.x += pv.x; v.y += pv.y; v.z += pv.z; v.w += pv.w;
        }
      }
      if (SILU) v = silu4(v);
      *(float4*)(&As[m][q]) = v;
    }
  }
  __syncthreads();
  const int lane = tid & 63;
  const int m0 = (tid >> 6) * 4;
  const float* Wrow = W + (size_t)(n0 + lane) * w_rs + k0;
  float acc0 = 0.f, acc1 = 0.f, acc2 = 0.f, acc3 = 0.f;
  constexpr int CHUNKS = KPB / 64;
  float4 wb[2][16];
#pragma unroll
  for (int c = 0; c < 16; ++c) wb[0][c] = *(const float4*)(Wrow + c * 4);
#pragma unroll
  for (int ch = 0; ch < CHUNKS; ++ch){
    constexpr int dummy = 0; (void)dummy;
    const int cur = ch & 1;
    if (ch + 1 < CHUNKS){
#pragma unroll
      for (int c = 0; c < 16; ++c)
        wb[cur ^ 1][c] = *(const float4*)(Wrow + (ch + 1) * 64 + c * 4);
    }
#pragma unroll
    for (int c = 0; c < 16; ++c){
      float4 wv = wb[cur][c];
      const int q = ch * 64 + c * 4;
      float4 a0 = *(const float4*)(&As[m0 + 0][q]);
      float4 a1 = *(const float4*)(&As[m0 + 1][q]);
      float4 a2 = *(const float4*)(&As[m0 + 2][q]);
      float4 a3 = *(const float4*)(&As[m0 + 3][q]);
      acc0 = fmaf(wv.x, a0.x, acc0); acc0 = fmaf(wv.y, a0.y, acc0);
      acc0 = fmaf(wv.z, a0.z, acc0); acc0 = fmaf(wv.w, a0.w, acc0);
      acc1 = fmaf(wv.x, a1.x, acc1); acc1 = fmaf(wv.y, a1.y, acc1);
      acc1 = fmaf(wv.z, a1.z, acc1); acc1 = fmaf(wv.w, a1.w, acc1);
      acc2 = fmaf(wv.x, a2.x, acc2); acc2 = fmaf(wv.y, a2.y, acc2);
      acc2 = fmaf(wv.z, a2.z, acc2); acc2 = fmaf(wv.w, a2.w, acc2);
      acc3 = fmaf(wv.x, a3.x, acc3); acc3 = fmaf(wv.y, a3.y, acc3);
      acc3 = fmaf(wv.z, a3.z, acc3); acc3 = fmaf(wv.w, a3.w, acc3);
    }
  }
  Cz[(size_t)(m0 + 0) * c_rs + n0 + lane] = acc0;
  Cz[(size_t)(m0 + 1) * c_rs + n0 + lane] = acc1;
  Cz[(size_t)(m0 + 2) * c_rs + n0 + lane] = acc2;
  Cz[(size_t)(m0 + 3) * c_rs + n0 + lane] = acc3;
}

template<int KPB, int NZ, bool SILU>
__global__ __launch_bounds__(256) void k_gemv_ms(
    const float* __restrict__ A, int a_rs, int a_bs, int pz,
    const float* __restrict__ abias,
    const float* __restrict__ W, int w_rs, int w_bs,
    float* __restrict__ C, int c_rs, int c_bs, int c_zs){
  const int bb = blockIdx.y;
  gemv_ms_core<KPB, NZ, SILU>(A + (size_t)bb * a_bs, a_rs, pz, abias,
      W + (size_t)bb * w_bs, w_rs,
      C + (size_t)blockIdx.z * c_zs + (size_t)bb * c_bs, c_rs,
      blockIdx.x * 64, blockIdx.z * KPB);
}

// QKV fused: blockIdx.y selects weight matrix / output slab.
template<int KPB>
__global__ __launch_bounds__(256) void k_gemv_ms3(
    const float* __restrict__ A, const float* __restrict__ W0,
    const float* __restrict__ W1, const float* __restrict__ W2,
    float* __restrict__ C){
  const int y = blockIdx.y;
  const float* W = (y == 0) ? W0 : ((y == 1) ? W1 : W2);
  gemv_ms_core<KPB, 0, false>(A, DIM, 0, nullptr, W, DIM,
      C + ((size_t)y * 16 + blockIdx.z) * (BATCH * DIM), DIM,
      blockIdx.x * 64, blockIdx.z * KPB);
}

// lm_head partial combine: out[i] = P[0][i] + P[1][i]
__global__ __launch_bounds__(256) void k_fin2(const float* __restrict__ P,
                                              float* __restrict__ out){
  int i = blockIdx.x * 256 + threadIdx.x;
  out[i] = P[i] + P[(size_t)BATCH * VOCAB + i];
}

// Self-attention per (b,h). Folds the 16 QKV k-split partials (+bias),
// writes new k/v to d_out, attends over 513 keys (float4-vectorized,
// 4 rows per wave-iter, prefetched). Mask bias is softmax-invariant.
__global__ __launch_bounds__(512) void k_self_attn(
    const float* __restrict__ Pqkv, const float* __restrict__ qb_,
    const float* __restrict__ kb_, const float* __restrict__ vb_,
    const float* __restrict__ pk, const float* __restrict__ pv,
    float* __restrict__ satt, float* __restrict__ out_k,
    float* __restrict__ out_v){
  __shared__ float qs[64], ks[64], vs[64];
  __shared__ float sc[513];
  __shared__ float red1[8], red2[8];
  __shared__ float o8[8][64];
  const int bh = blockIdx.x, b = bh >> 4, h = bh & 15;
  const int tid = threadIdx.x, w = tid >> 6, lane = tid & 63;
  const int hd = h * HDIM + lane;
  if (w < 3){
    const float* Pz = Pqkv + (size_t)w * (16 * BATCH * DIM);
    const float* bias = (w == 0) ? qb_ : ((w == 1) ? kb_ : vb_);
    float v = bias[hd];
#pragma unroll
    for (int z = 0; z < 16; ++z)
      v += Pz[(size_t)z * (BATCH * DIM) + b * DIM + hd];
    if (w == 0) qs[lane] = v * SCALE;
    else if (w == 1){ ks[lane] = v; out_k[b * DIM + hd] = v; }
    else { vs[lane] = v; out_v[b * DIM + hd] = v; }
  }
  __syncthreads();
  const int jj = lane >> 4, c = lane & 15;
  float4 q4 = *(const float4*)(&qs[c * 4]);
  const float* kbase = pk + (size_t)b * NCACHE * DIM + h * HDIM + c * 4;
  {
    float4 nk = *(const float4*)(kbase + (size_t)(w * 4 + jj) * DIM);
    for (int it = 0; it < 16; ++it){
      int j = it * 32 + w * 4 + jj;
      float4 K4 = nk;
      if (it < 15) nk = *(const float4*)(kbase + (size_t)(j + 32) * DIM);
      float r = q4.x * K4.x;
      r = fmaf(q4.y, K4.y, r); r = fmaf(q4.z, K4.z, r); r = fmaf(q4.w, K4.w, r);
      r += __shfl_xor(r, 1, 64); r += __shfl_xor(r, 2, 64);
      r += __shfl_xor(r, 4, 64); r += __shfl_xor(r, 8, 64);
      if (c == 0) sc[j] = r;
    }
  }
  if (w == 0 && lane < 16){
    float4 k4 = *(const float4*)(&ks[lane * 4]);
    float r = q4.x * k4.x;
    r = fmaf(q4.y, k4.y, r); r = fmaf(q4.z, k4.z, r); r = fmaf(q4.w, k4.w, r);
    r += __shfl_xor(r, 1, 64); r += __shfl_xor(r, 2, 64);
    r += __shfl_xor(r, 4, 64); r += __shfl_xor(r, 8, 64);
    if (lane == 0) sc[512] = r;
  }
  __syncthreads();
  float lm = -1e30f;
  for (int j2 = tid; j2 < 513; j2 += 512) lm = fmaxf(lm, sc[j2]);
  lm = wave_reduce_max(lm);
  if (lane == 0) red1[w] = lm;
  __syncthreads();
  float bm = red1[0];
#pragma unroll
  for (int ww = 1; ww < 8; ++ww) bm = fmaxf(bm, red1[ww]);
  float ls = 0.f;
  for (int j2 = tid; j2 < 513; j2 += 512){
    float e = expf(sc[j2] - bm);
    sc[j2] = e;
    ls += e;
  }
  ls = wave_reduce_sum(ls);
  if (lane == 0) red2[w] = ls;
  __syncthreads();
  float tot = 0.f;
#pragma unroll
  for (int ww = 0; ww < 8; ++ww) tot += red2[ww];
  float inv = 1.f / tot;
  const float* vbase = pv + (size_t)b * NCACHE * DIM + h * HDIM + c * 4;
  float4 acc; acc.x = 0.f; acc.y = 0.f; acc.z = 0.f; acc.w = 0.f;
  {
    float4 nv = *(const float4*)(vbase + (size_t)(w * 4 + jj) * DIM);
    for (int it = 0; it < 16; ++it){
      int j = it * 32 + w * 4 + jj;
      float4 V4 = nv;
      if (it < 15) nv = *(const float4*)(vbase + (size_t)(j + 32) * DIM);
      float pj = sc[j];
      acc.x = fmaf(pj, V4.x, acc.x); acc.y = fmaf(pj, V4.y, acc.y);
      acc.z = fmaf(pj, V4.z, acc.z); acc.w = fmaf(pj, V4.w, acc.w);
    }
  }
  if (w == 0 && lane < 16){
    float p512 = sc[512];
    float4 v4 = *(const float4*)(&vs[lane * 4]);
    acc.x = fmaf(p512, v4.x, acc.x); acc.y = fmaf(p512, v4.y, acc.y);
    acc.z = fmaf(p512, v4.z, acc.z); acc.w = fmaf(p512, v4.w, acc.w);
  }
  acc.x += __shfl_xor(acc.x, 16, 64); acc.x += __shfl_xor(acc.x, 32, 64);
  acc.y += __shfl_xor(acc.y, 16, 64); acc.y += __shfl_xor(acc.y, 32, 64);
  acc.z += __shfl_xor(acc.z, 16, 64); acc.z += __shfl_xor(acc.z, 32, 64);
  acc.w += __shfl_xor(acc.w, 16, 64); acc.w += __shfl_xor(acc.w, 32, 64);
  if (lane < 16){
    o8[w][lane * 4 + 0] = acc.x; o8[w][lane * 4 + 1] = acc.y;
    o8[w][lane * 4 + 2] = acc.z; o8[w][lane * 4 + 3] = acc.w;
  }
  __syncthreads();
  if (tid < 64){
    float s2 = 0.f;
#pragma unroll
    for (int ww = 0; ww < 8; ++ww) s2 += o8[ww][tid];
    satt[b * DIM + h * HDIM + tid] = s2 * inv;
  }
}

// h = LayerNorm(res + sum_z P[z] + obias) * w + b
template<int NZ>
__global__ __launch_bounds__(256) void k_add_ln_pz(
    const float* __restrict__ res, const float* __restrict__ P, int zs,
    const float* __restrict__ obias, const float* __restrict__ w,
    const float* __restrict__ bln, float* __restrict__ outh){
  __shared__ float r1[4], r2[4];
  int b = blockIdx.x, tid = threadIdx.x, wave = tid >> 6, lane = tid & 63;
  float4 rv = ((const float4*)(res + (size_t)b * DIM))[tid];
  float4 ob = ((const float4*)obias)[tid];
  float v0 = rv.x + ob.x, v1 = rv.y + ob.y, v2 = rv.z + ob.z, v3 = rv.w + ob.w;
#pragma unroll
  for (int z = 0; z < NZ; ++z){
    float4 pz = ((const float4*)(P + (size_t)z * zs + (size_t)b * DIM))[tid];
    v0 += pz.x; v1 += pz.y; v2 += pz.z; v3 += pz.w;
  }
  float s = v0 + v1 + v2 + v3;
  float sq = v0 * v0 + v1 * v1 + v2 * v2 + v3 * v3;
  s = wave_reduce_sum(s); sq = wave_reduce_sum(sq);
  if (lane == 0){ r1[wave] = s; r2[wave] = sq; }
  __syncthreads();
  float ts = r1[0] + r1[1] + r1[2] + r1[3];
  float tq = r2[0] + r2[1] + r2[2] + r2[3];
  float mean = ts * (1.f / DIM);
  float var = tq * (1.f / DIM) - mean * mean;
  float rstd = rsqrtf(var + 1e-5f);
  float4 wv = ((const float4*)w)[tid], bv = ((const float4*)bln)[tid];
  float4 o;
  o.x = (v0 - mean) * rstd * wv.x + bv.x;
  o.y = (v1 - mean) * rstd * wv.y + bv.y;
  o.z = (v2 - mean) * rstd * wv.z + bv.z;
  o.w = (v3 - mean) * rstd * wv.w + bv.w;
  ((float4*)(outh + (size_t)b * DIM))[tid] = o;
}

// g[b][h][c] = sum_d qv[b][hd] * kw[hd][c], qv = (sum_z Pcq + caqb)*SCALE
__global__ __launch_bounds__(256) void k_gmat2(
    const float* __restrict__ Pcq, const float* __restrict__ caqb,
    const float* __restrict__ kw, float* __restrict__ g){
  __shared__ float qsT[64][16];   // [d][b]
  __shared__ float Ps[4][16][64];
  const int h = blockIdx.y, c0 = blockIdx.x * 64;
  const int tid = threadIdx.x, lane = tid & 63, wave = tid >> 6;
  {
    const int b = tid >> 4, q0 = (tid & 15) * 4;
    float4 v = *(const float4*)(caqb + h * HDIM + q0);
#pragma unroll
    for (int z = 0; z < 16; ++z){
      float4 pv = *(const float4*)(Pcq + (size_t)z * (BATCH * DIM) +
                                   (size_t)b * DIM + h * HDIM + q0);
      v.x += pv.x; v.y += pv.y; v.z += pv.z; v.w += pv.w;
    }
    qsT[q0 + 0][b] = v.x * SCALE; qsT[q0 + 1][b] = v.y * SCALE;
    qsT[q0 + 2][b] = v.z * SCALE; qsT[q0 + 3][b] = v.w * SCALE;
  }
  __syncthreads();
  float wv[16];
#pragma unroll
  for (int dd = 0; dd < 16; ++dd)
    wv[dd] = kw[(size_t)(h * HDIM + wave * 16 + dd) * DIM + c0 + lane];
  float acc[16];
#pragma unroll
  for (int m = 0; m < 16; ++m) acc[m] = 0.f;
#pragma unroll
  for (int dd = 0; dd < 16; ++dd){
    const int d = wave * 16 + dd;
    float4 a0 = *(const float4*)(&qsT[d][0]);
    float4 a1 = *(const float4*)(&qsT[d][4]);
    float4 a2 = *(const float4*)(&qsT[d][8]);
    float4 a3 = *(const float4*)(&qsT[d][12]);
    float wd = wv[dd];
    acc[0] = fmaf(wd, a0.x, acc[0]);  acc[1] = fmaf(wd, a0.y, acc[1]);
    acc[2] = fmaf(wd, a0.z, acc[2]);  acc[3] = fmaf(wd, a0.w, acc[3]);
    acc[4] = fmaf(wd, a1.x, acc[4]);  acc[5] = fmaf(wd, a1.y, acc[5]);
    acc[6] = fmaf(wd, a1.z, acc[6]);  acc[7] = fmaf(wd, a1.w, acc[7]);
    acc[8] = fmaf(wd, a2.x, acc[8]);  acc[9] = fmaf(wd, a2.y, acc[9]);
    acc[10] = fmaf(wd, a2.z, acc[10]); acc[11] = fmaf(wd, a2.w, acc[11]);
    acc[12] = fmaf(wd, a3.x, acc[12]); acc[13] = fmaf(wd, a3.y, acc[13]);
    acc[14] = fmaf(wd, a3.z, acc[14]); acc[15] = fmaf(wd, a3.w, acc[15]);
  }
#pragma unroll
  for (int m = 0; m < 16; ++m) Ps[wave][m][lane] = acc[m];
  __syncthreads();
  const int nl = tid & 63, mg = (tid >> 6) * 4;
#pragma unroll
  for (int mm = 0; mm < 4; ++mm){
    int m = mg + mm;
    float r = Ps[0][m][nl] + Ps[1][m][nl] + Ps[2][m][nl] + Ps[3][m][nl];
    g[((size_t)m * NH + h) * DIM + c0 + nl] = r;
  }
}

// softmax over rows of 512; input = sum of 8 k-split partials
__global__ __launch_bounds__(512) void k_softmax512p8(const float* __restrict__ S,
                                                      float* __restrict__ p){
  __shared__ float red[8];
  const int row = blockIdx.x;
  const int tid = threadIdx.x, wave = tid >> 6, lane = tid & 63;
  float v = 0.f;
#pragma unroll
  for (int z = 0; z < 8; ++z)
    v += S[(size_t)z * (BATCH * NH * SRCLEN) + (size_t)row * SRCLEN + tid];
  float m = wave_reduce_max(v);
  if (lane == 0) red[wave] = m;
  __syncthreads();
  float bm = red[0];
#pragma unroll
  for (int w = 1; w < 8; ++w) bm = fmaxf(bm, red[w]);
  float e = expf(v - bm);
  __syncthreads();
  float ls = wave_reduce_sum(e);
  if (lane == 0) red[wave] = ls;
  __syncthreads();
  float tot = 0.f;
#pragma unroll
  for (int w = 0; w < 8; ++w) tot += red[w];
  p[(size_t)row * SRCLEN + tid] = e / tot;
}

// ctx[b][h][c] = sum_j p[b][h][j] * enc[b][j][c]  (p staged transposed in LDS)
__global__ __launch_bounds__(256) void k_ctx(const float* __restrict__ p,
                                             const float* __restrict__ enc,
                                             float* __restrict__ ctx){
  __shared__ float pT[SRCLEN][16];
  __shared__ float Ps[4][16][64];
  const int b = blockIdx.y, c0 = blockIdx.x * 64;
  const int tid = threadIdx.x, lane = tid & 63, wave = tid >> 6;
  {
    const int h = tid >> 4, jp = (tid & 15) * 4;
#pragma unroll
    for (int t = 0; t < 8; ++t){
      const int j = jp + t * 64;
      float4 v = *(const float4*)(p + ((size_t)b * NH + h) * SRCLEN + j);
      pT[j + 0][h] = v.x; pT[j + 1][h] = v.y;
      pT[j + 2][h] = v.z; pT[j + 3][h] = v.w;
    }
  }
  __syncthreads();
  const float* ep = enc + (size_t)b * SRCLEN * DIM + c0 + lane;
  const int jb = wave * 128;
  float acc[16];
#pragma unroll
  for (int m = 0; m < 16; ++m) acc[m] = 0.f;
  float cur[8], nxt[8];
#pragma unroll
  for (int i = 0; i < 8; ++i) cur[i] = ep[(size_t)(jb + i) * DIM];
#pragma unroll
  for (int t = 0; t < 16; ++t){
    if (t < 15){
#pragma unroll
      for (int i = 0; i < 8; ++i)
        nxt[i] = ep[(size_t)(jb + (t + 1) * 8 + i) * DIM];
    }
#pragma unroll
    for (int i = 0; i < 8; ++i){
      const int j = jb + t * 8 + i;
      float4 p0 = *(const float4*)(&pT[j][0]);
      float4 p1 = *(const float4*)(&pT[j][4]);
      float4 p2 = *(const float4*)(&pT[j][8]);
      float4 p3 = *(const float4*)(&pT[j][12]);
      float ev = cur[i];
      acc[0] = fmaf(p0.x, ev, acc[0]);  acc[1] = fmaf(p0.y, ev, acc[1]);
      acc[2] = fmaf(p0.z, ev, acc[2]);  acc[3] = fmaf(p0.w, ev, acc[3]);
      acc[4] = fmaf(p1.x, ev, acc[4]);  acc[5] = fmaf(p1.y, ev, acc[5]);
      acc[6] = fmaf(p1.z, ev, acc[6]);  acc[7] = fmaf(p1.w, ev, acc[7]);
      acc[8] = fmaf(p2.x, ev, acc[8]);  acc[9] = fmaf(p2.y, ev, acc[9]);
      acc[10] = fmaf(p2.z, ev, acc[10]); acc[11] = fmaf(p2.w, ev, acc[11]);
      acc[12] = fmaf(p3.x, ev, acc[12]); acc[13] = fmaf(p3.y, ev, acc[13]);
      acc[14] = fmaf(p3.z, ev, acc[14]); acc[15] = fmaf(p3.w, ev, acc[15]);
    }
#pragma unroll
    for (int i = 0; i < 8; ++i) cur[i] = nxt[i];
  }
#pragma unroll
  for (int m = 0; m < 16; ++m) Ps[wave][m][lane] = acc[m];
  __syncthreads();
  const int nl = tid & 63, mg = (tid >> 6) * 4;
#pragma unroll
  for (int mm = 0; mm < 4; ++mm){
    int m = mg + mm;
    float r = Ps[0][m][nl] + Ps[1][m][nl] + Ps[2][m][nl] + Ps[3][m][nl];
    ctx[((size_t)b * NH + m) * DIM + c0 + nl] = r;
  }
}

extern "C" void kernel_launch(void* const* d_in, const int* in_sizes, int n_in,
                              void* d_out, int out_size, void* d_ws, size_t ws_size,
                              hipStream_t stream){
  const float* de   = (const float*)d_in[0];
  const float* enc  = (const float*)d_in[1];
  const float* pk   = (const float*)d_in[2];
  const float* pv   = (const float*)d_in[3];
  const int*   cl   = (const int*)d_in[4];
  const float* pe   = (const float*)d_in[5];
  const float* saqw = (const float*)d_in[6];
  const float* sakw = (const float*)d_in[7];
  const float* savw = (const float*)d_in[8];
  const float* saow = (const float*)d_in[9];
  const float* caqw = (const float*)d_in[10];
  const float* cakw = (const float*)d_in[11];
  const float* cavw = (const float*)d_in[12];
  const float* caow = (const float*)d_in[13];
  const float* saqb = (const float*)d_in[14];
  const float* sakb = (const float*)d_in[15];
  const float* savb = (const float*)d_in[16];
  const float* saob = (const float*)d_in[17];
  const float* caqb = (const float*)d_in[18];
  const float* cakb = (const float*)d_in[19];
  const float* cavb = (const float*)d_in[20];
  const float* caob = (const float*)d_in[21];
  const float* fc1w = (const float*)d_in[22];
  const float* fc1b = (const float*)d_in[23];
  const float* fc2w = (const float*)d_in[24];
  const float* fc2b = (const float*)d_in[25];
  const float* ln1w = (const float*)d_in[26];
  const float* ln2w = (const float*)d_in[27];
  const float* ln3w = (const float*)d_in[28];
  const float* ln1b = (const float*)d_in[29];
  const float* ln2b = (const float*)d_in[30];
  const float* ln3b = (const float*)d_in[31];
  const float* lmw  = (const float*)d_in[32];
  float* out = (float*)d_out;
  float* ws  = (float*)d_ws;

  float* h    = ws;              // [16][1024]
  float* satt = ws + 16384;      // [16][1024]
  float* g    = ws + 32768;      // [16][16][1024]
  float* p    = ws + 294912;     // [256][512]
  float* ctx  = ws + 425984;     // [16][16][1024]
  float* Po   = ws + 688128;     // [16][16][1024]
  float* Pcq  = ws + 950272;     // [16][16][1024]
  float* Pvo  = ws + 1212416;    // [16][16][1024]
  float* Pco  = ws + 1474560;    // [16][16][1024]
  float* Pf1  = ws + 1736704;    // [8][16][4096]
  float* Pf2  = ws + 2260992;    // [32][16][1024]
  float* s2   = ws + 2785280;    // [8][256][512]
  float* Pqkv = ws + 3833856;    // [3][16][16][1024]
  float* Plm  = ws + 4620288;    // [2][16][32000]

  float* out_k = out + 512000;   // [L][16][1024]
  float* out_v = out + 610304;   // [L][16][1024]

  k_embed<<<16, 256, 0, stream>>>(de, pe, cl, h);

  for (int i = 0; i < LYRS; ++i){
    size_t wo = (size_t)i * DIM * DIM;
    size_t bo = (size_t)i * DIM;
    float* ko = out_k + (size_t)i * BATCH * DIM;
    float* vo = out_v + (size_t)i * BATCH * DIM;
    // ---- self-attention ----
    k_gemv_ms3<64><<<dim3(16, 3, 16), 256, 0, stream>>>(h, saqw + wo, sakw + wo,
        savw + wo, Pqkv);
    k_self_attn<<<256, 512, 0, stream>>>(Pqkv, saqb + bo, sakb + bo, savb + bo,
        pk + (size_t)i * BATCH * NCACHE * DIM, pv + (size_t)i * BATCH * NCACHE * DIM,
        satt, ko, vo);
    k_gemv_ms<64, 0, false><<<dim3(16, 1, 16), 256, 0, stream>>>(satt, DIM, 0, 0,
        nullptr, saow + wo, DIM, 0, Po, DIM, 0, BATCH * DIM);
    k_add_ln_pz<16><<<16, 256, 0, stream>>>(h, Po, BATCH * DIM, saob + bo,
        ln1w + bo, ln1b + bo, h);
    // ---- cross-attention (K/V projections folded around the softmax) ----
    k_gemv_ms<64, 0, false><<<dim3(16, 1, 16), 256, 0, stream>>>(h, DIM, 0, 0,
        nullptr, caqw + wo, DIM, 0, Pcq, DIM, 0, BATCH * DIM);
    k_gmat2<<<dim3(16, 16), 256, 0, stream>>>(Pcq, caqb + bo, cakw + wo, g);
    k_gemv_ms<128, 0, false><<<dim3(8, 16, 8), 256, 0, stream>>>(g, DIM, NH * DIM,
        0, nullptr, enc, DIM, SRCLEN * DIM, s2, SRCLEN, NH * SRCLEN,
        BATCH * NH * SRCLEN);
    k_softmax512p8<<<256, 512, 0, stream>>>(s2, p);
    k_ctx<<<dim3(16, 16), 256, 0, stream>>>(p, enc, ctx);
    k_gemv_ms<64, 0, false><<<dim3(1, 16, 16), 256, 0, stream>>>(ctx, NH * DIM,
        DIM, 0, nullptr, cavw + wo, DIM, HDIM * DIM, Pvo, DIM, HDIM, BATCH * DIM);
    k_gemv_ms<64, 16, false><<<dim3(16, 1, 16), 256, 0, stream>>>(Pvo, DIM, 0,
        BATCH * DIM, cavb + bo, caow + wo, DIM, 0, Pco, DIM, 0, BATCH * DIM);
    k_add_ln_pz<16><<<16, 256, 0, stream>>>(h, Pco, BATCH * DIM, caob + bo,
        ln2w + bo, ln2b + bo, h);
    // ---- FFN ----
    k_gemv_ms<128, 0, false><<<dim3(64, 1, 8), 256, 0, stream>>>(h, DIM, 0, 0,
        nullptr, fc1w + (size_t)i * FFNDIM * DIM, DIM, 0, Pf1, FFNDIM, 0,
        BATCH * FFNDIM);
    k_gemv_ms<128, 8, true><<<dim3(16, 1, 32), 256, 0, stream>>>(Pf1, FFNDIM, 0,
        BATCH * FFNDIM, fc1b + (size_t)i * FFNDIM,
        fc2w + (size_t)i * DIM * FFNDIM, FFNDIM, 0, Pf2, DIM, 0, BATCH * DIM);
    k_add_ln_pz<32><<<16, 256, 0, stream>>>(h, Pf2, BATCH * DIM, fc2b + bo,
        ln3w + bo, ln3b + bo, h);
  }
  // ---- lm_head ----
  k_gemv_ms<512, 0, false><<<dim3(VOCAB / 64, 1, 2), 256, 0, stream>>>(h, DIM, 0,
      0, nullptr, lmw, DIM, 0, Plm, VOCAB, 0, BATCH * VOCAB);
  k_fin2<<<BATCH * VOCAB / 256, 256, 0, stream>>>(Plm, out);
}